// Round 9
// baseline (1208.214 us; speedup 1.0000x reference)
//
#include <hip/hip_runtime.h>
#include <hip/hip_fp16.h>

typedef unsigned int u32;
typedef _Float16 h2f __attribute__((ext_vector_type(2)));

#define BB 128
#define TT 512
#define DD 64
#define NBL 32
#define GIN 2080

// DPP: quad_perm xor1=0xB1 xor2=0x4E xor3=0x1B; half_mirror(xor7)=0x141;
// row_mirror(xor15)=0x140. All VALU-pipe.
template <int CTRL>
__device__ __forceinline__ float dpp_mov_f(float x) {
  return __builtin_bit_cast(
      float, __builtin_amdgcn_update_dpp(0, __builtin_bit_cast(int, x), CTRL,
                                         0xF, 0xF, true));
}
template <int CTRL>
__device__ __forceinline__ u32 dpp_mov_u(u32 x) {
  return (u32)__builtin_amdgcn_update_dpp(0, (int)x, CTRL, 0xF, 0xF, true);
}
template <int CTRL>
__device__ __forceinline__ float dpp_add_f(float x) {
  return x + dpp_mov_f<CTRL>(x);
}
__device__ __forceinline__ float swz_add16(float x) {  // xor16 within 32
  return x + __builtin_bit_cast(float, __builtin_amdgcn_ds_swizzle(
                                           __builtin_bit_cast(int, x), 0x401F));
}
__device__ __forceinline__ float bpermf(int addr, float x) {
  return __builtin_bit_cast(
      float, __builtin_amdgcn_ds_bpermute(addr, __builtin_bit_cast(int, x)));
}
__device__ __forceinline__ int uni_i(int v) {
  return __builtin_amdgcn_readfirstlane(v);
}

// sign of e_i * e_j in Cl(4,1): 1 if negative
__device__ inline int gp_negbit(int i, int j) {
  int sw = 0;
#pragma unroll
  for (int b = 0; b < 5; ++b)
    if ((j >> b) & 1) sw += __popc(i >> (b + 1));
  return (sw ^ ((i & j) >> 4)) & 1;  // METRIC[4] = -1
}

__device__ inline float fdot2f(u32 a, u32 b, float acc) {
#if __has_builtin(__builtin_amdgcn_fdot2)
  return __builtin_amdgcn_fdot2(__builtin_bit_cast(h2f, a),
                                __builtin_bit_cast(h2f, b), acc, false);
#else
  h2f av = __builtin_bit_cast(h2f, a), bv = __builtin_bit_cast(h2f, b);
  return acc + (float)av.x * (float)bv.x + (float)av.y * (float)bv.y;
#endif
}

__device__ inline u32 pkf16(float a, float b) {
  return __builtin_bit_cast(u32, __builtin_amdgcn_cvt_pkrtz(a, b));
}

// Packed GP term (algebra identical to R6/R8-verified GPTERM):
//   b0  += t0*E0 + t1*E1   = fdot2( (t0,t1), (E0,E1) )
//   b1v += t0*E1 - t1*E0   = fdot2( (t0,-t1), (E1,E0) )
// where (t0,t1) = rpk[M] ^ mA[M] (per-lane f16 sign masks), E = packed
// (u0,u1) of lane l^M via DPP, swap via alignbit.
#define GPTERM2(M, RPK, E)                                 \
  do {                                                     \
    u32 TA = (RPK) ^ mA[(M)];                              \
    u32 TB = TA ^ 0x80000000u;                             \
    u32 Es = __builtin_amdgcn_alignbit((E), (E), 16);      \
    b0 = fdot2f(TA, (E), b0);                              \
    b1v = fdot2f(TB, Es, b1v);                             \
  } while (0)

#define STEP(P, XI)                                                           \
  do {                                                                        \
    const int pn = (P) ^ 1;                                                   \
    /* uniform packed r row: 16 dwords via scalar loads from ws table */      \
    const u32* wsr = wsu + (XI) * 16;                                         \
    u32 rpk0 = (u32)uni_i((int)wsr[0]);                                       \
    u32 rpk1 = (u32)uni_i((int)wsr[1]);                                       \
    u32 rpk2 = (u32)uni_i((int)wsr[2]);                                       \
    u32 rpk3 = (u32)uni_i((int)wsr[3]);                                       \
    u32 rpk4 = (u32)uni_i((int)wsr[4]);                                       \
    u32 rpk5 = (u32)uni_i((int)wsr[5]);                                       \
    u32 rpk6 = (u32)uni_i((int)wsr[6]);                                       \
    u32 rpk7 = (u32)uni_i((int)wsr[7]);                                       \
    u32 rpk8 = (u32)uni_i((int)wsr[8]);                                       \
    u32 rpk9 = (u32)uni_i((int)wsr[9]);                                       \
    u32 rpk10 = (u32)uni_i((int)wsr[10]);                                     \
    u32 rpk11 = (u32)uni_i((int)wsr[11]);                                     \
    u32 rpk12 = (u32)uni_i((int)wsr[12]);                                     \
    u32 rpk13 = (u32)uni_i((int)wsr[13]);                                     \
    u32 rpk14 = (u32)uni_i((int)wsr[14]);                                     \
    u32 rpk15 = (u32)uni_i((int)wsr[15]);                                     \
    /* gate: 4x contiguous b128 LDS reads (P = 256j + 4l) + 64 f16 dot2 */    \
    float a0 = 0.f, a1 = 0.f, a2 = 0.f, a3 = 0.f;                             \
    _Pragma("unroll") for (int jq = 0; jq < 4; ++jq) {                        \
      uint4 hv = *(const uint4*)&h16[(P)][256 * jq + 4 * l];                  \
      a0 = fdot2f(gw[0][4 * jq + 0], hv.x, a0);                               \
      a0 = fdot2f(gw[0][4 * jq + 1], hv.y, a0);                               \
      a0 = fdot2f(gw[0][4 * jq + 2], hv.z, a0);                               \
      a0 = fdot2f(gw[0][4 * jq + 3], hv.w, a0);                               \
      a1 = fdot2f(gw[1][4 * jq + 0], hv.x, a1);                               \
      a1 = fdot2f(gw[1][4 * jq + 1], hv.y, a1);                               \
      a1 = fdot2f(gw[1][4 * jq + 2], hv.z, a1);                               \
      a1 = fdot2f(gw[1][4 * jq + 3], hv.w, a1);                               \
      a2 = fdot2f(gw[2][4 * jq + 0], hv.x, a2);                               \
      a2 = fdot2f(gw[2][4 * jq + 1], hv.y, a2);                               \
      a2 = fdot2f(gw[2][4 * jq + 2], hv.z, a2);                               \
      a2 = fdot2f(gw[2][4 * jq + 3], hv.w, a2);                               \
      a3 = fdot2f(gw[3][4 * jq + 0], hv.x, a3);                               \
      a3 = fdot2f(gw[3][4 * jq + 1], hv.y, a3);                               \
      a3 = fdot2f(gw[3][4 * jq + 2], hv.z, a3);                               \
      a3 = fdot2f(gw[3][4 * jq + 3], hv.w, a3);                               \
    }                                                                         \
    /* reduce over 32-lane half: xor1,2,(4),(8),16 */                         \
    a0 = dpp_add_f<0xB1>(a0); a0 = dpp_add_f<0x4E>(a0);                       \
    a0 = dpp_add_f<0x141>(a0); a0 = dpp_add_f<0x140>(a0); a0 = swz_add16(a0); \
    a1 = dpp_add_f<0xB1>(a1); a1 = dpp_add_f<0x4E>(a1);                       \
    a1 = dpp_add_f<0x141>(a1); a1 = dpp_add_f<0x140>(a1); a1 = swz_add16(a1); \
    a2 = dpp_add_f<0xB1>(a2); a2 = dpp_add_f<0x4E>(a2);                       \
    a2 = dpp_add_f<0x141>(a2); a2 = dpp_add_f<0x140>(a2); a2 = swz_add16(a2); \
    a3 = dpp_add_f<0xB1>(a3); a3 = dpp_add_f<0x4E>(a3);                       \
    a3 = dpp_add_f<0x141>(a3); a3 = dpp_add_f<0x140>(a3); a3 = swz_add16(a3); \
    float selA = s ? a1 : a0;                                                 \
    float selB = s ? a3 : a2;                                                 \
    float zsum = selA + bpermf(bp32, selB);                                   \
    float rcsel = ((XI) == 0)   ? rcv0                                        \
                  : ((XI) == 1) ? rcv1                                        \
                  : ((XI) == 2) ? rcv2                                        \
                                : rcv3;                                       \
    float invsel = ((XI) == 0)   ? iv0                                        \
                   : ((XI) == 1) ? iv1                                        \
                   : ((XI) == 2) ? iv2                                        \
                                 : iv3;                                       \
    float g = 1.f / (1.f + exp2f(-1.44269504f * (zsum + rcsel)));             \
    /* GP: 16-lane butterfly on packed (u0,u1), fdot2 accumulation (f32) */   \
    u32 pkE = pkf16(u0, u1);                                                  \
    float b0 = 0.f, b1v = 0.f;                                                \
    GPTERM2(0, rpk0, pkE);                                                    \
    {                                                                         \
      u32 e;                                                                  \
      e = dpp_mov_u<0xB1>(pkE); GPTERM2(1, rpk1, e);                          \
      e = dpp_mov_u<0x4E>(pkE); GPTERM2(2, rpk2, e);                          \
      e = dpp_mov_u<0x1B>(pkE); GPTERM2(3, rpk3, e);                          \
      u32 y = dpp_mov_u<0x141>(pkE);                                          \
      GPTERM2(7, rpk7, y);                                                    \
      e = dpp_mov_u<0xB1>(y); GPTERM2(6, rpk6, e);                            \
      e = dpp_mov_u<0x4E>(y); GPTERM2(5, rpk5, e);                            \
      e = dpp_mov_u<0x1B>(y); GPTERM2(4, rpk4, e);                            \
      u32 y2 = dpp_mov_u<0x140>(pkE);                                         \
      GPTERM2(15, rpk15, y2);                                                 \
      e = dpp_mov_u<0xB1>(y2); GPTERM2(14, rpk14, e);                         \
      e = dpp_mov_u<0x4E>(y2); GPTERM2(13, rpk13, e);                         \
      e = dpp_mov_u<0x1B>(y2); GPTERM2(12, rpk12, e);                         \
      u32 z0 = dpp_mov_u<0x141>(y2);                                          \
      GPTERM2(8, rpk8, z0);                                                   \
      e = dpp_mov_u<0xB1>(z0); GPTERM2(9, rpk9, e);                           \
      e = dpp_mov_u<0x4E>(z0); GPTERM2(10, rpk10, e);                         \
      e = dpp_mov_u<0x1B>(z0); GPTERM2(11, rpk11, e);                         \
    }                                                                         \
    /* gated update (r-norm folded post-dot) + mnorm over 16-lane row */      \
    float gi = g * invsel;                                                    \
    float om = 1.f - g;                                                       \
    float nu0 = fmaf(gi, b0, om * u0);                                        \
    float nu1 = fmaf(gi, b1v, om * u1);                                       \
    float sq = fmaf(nu1, nu1, nu0 * nu0);                                     \
    sq = dpp_add_f<0xB1>(sq);                                                 \
    sq = dpp_add_f<0x4E>(sq);                                                 \
    sq = dpp_add_f<0x141>(sq);                                                \
    sq = dpp_add_f<0x140>(sq);                                                \
    float sc = 1.f / (sqrtf(sq) + 1e-8f);                                     \
    u0 = nu0 * sc;                                                            \
    u1 = nu1 * sc;                                                            \
    /* one b32 store per lane: even c packs pair c/2, odd packs c/2+8 */      \
    float v0 = dpp_mov_f<0xB1>(u0);                                           \
    float v1 = dpp_mov_f<0xB1>(u1);                                           \
    h16[pn][Pst] = (c & 1) ? pkf16(v1, u1) : pkf16(u0, v0);                   \
    __syncthreads();                                                          \
  } while (0)

// tiny pre-kernel: packed raw emb rows -> ws table (4 rows x 16 f16x2)
__global__ void versor_pre(const float* __restrict__ emb, u32* __restrict__ wsu) {
  int e = threadIdx.x;
  if (e < 4) {
    float v[NBL];
    for (int i = 0; i < NBL; ++i) v[i] = emb[e * NBL + i];
    for (int m = 0; m < 16; ++m) wsu[e * 16 + m] = pkf16(v[m], v[m + 16]);
  }
}

// Physical LDS layout for the gate state (per buffer, 1024 dwords):
// logical dword L = 64*m + dd (pair m of row dd, f16x2 = blades 2m,2m+1);
// lane l covers L in [16l,16l+16); entry (j,k) -> physical 256j + 4l + k.
// Gate reads are 4x perfectly-contiguous ds_read_b128 (16B/lane).
__global__ __launch_bounds__(1024, 4)
__attribute__((amdgpu_waves_per_eu(4, 4))) void versor_fused(
    const int* __restrict__ x, const float* __restrict__ emb,
    const float* __restrict__ gate_w, const float* __restrict__ gate_b,
    const float* __restrict__ w1, const float* __restrict__ b1g,
    const float* __restrict__ ln_g, const float* __restrict__ ln_b,
    const float* __restrict__ w2, const float* __restrict__ b2,
    const u32* __restrict__ wsu, float* __restrict__ out) {
  __shared__ float rn[4][NBL];   // normalized emb rows (init/rc only)
  __shared__ float inv_lds[4];   // 1/(||emb_row||+eps)
  __shared__ float rc[4][DD];    // r-part of gate, pre-dotted
  __shared__ __align__(16) u32 h16[2][1024];  // f16x2 state, interleaved
  __shared__ __align__(16) float hs[2048];    // final h for head
  __shared__ float redA[16][2];
  __shared__ float redB[16][2];

  const int b = blockIdx.x;
  const int tid = threadIdx.x;
  const int w = tid >> 6;       // wave 0..15
  const int l = tid & 63;       // lane
  const int rl = l >> 4;        // row-in-wave 0..3
  const int d = (w << 2) + rl;  // this lane's state row
  const int c = l & 15;         // owner blade pair: owns {c, c+16}
  const int H = l >> 5;         // half (gate row-group)
  const int s = rl & 1;         // row-within-halfgroup
  const int bp32 = ((l ^ 32) << 2);
  // store address: P(m,d) = 256*((d&15)>>2) + 16*m + 4*(d>>4) + (d&3)
  const int mst = (c >> 1) + ((c & 1) << 3);
  const int Pst = 256 * ((d & 15) >> 2) + 16 * mst + 4 * (d >> 4) + (d & 3);

  // ---- init: normalized embeddings + inverse norms ----
  if (tid < 4) {
    float v[NBL];
    float sum = 0.f;
    for (int i = 0; i < NBL; ++i) {
      v[i] = emb[tid * NBL + i];
      sum += v[i] * v[i];
    }
    float sc = 1.f / (sqrtf(sum) + 1e-8f);
    inv_lds[tid] = sc;
    for (int i = 0; i < NBL; ++i) rn[tid][i] = v[i] * sc;
  }
  {  // h0 = e0: logical L = tid -> m = L>>6, dd = L&63
    int m = tid >> 6, dd = tid & 63;
    int P = 256 * ((dd & 15) >> 2) + 16 * m + 4 * (dd >> 4) + (dd & 3);
    h16[0][P] = (m == 0) ? 0x00003C00u : 0u;  // pack(1.0h, 0)
  }
  __syncthreads();

  // ---- rc[e][row] = sum_i gate_w[row][2048+i] * rn_normalized[e][i] ----
  if (tid < 256) {
    int e = tid >> 6, row = tid & 63;
    float sum = 0.f;
    for (int i = 0; i < NBL; ++i) sum += gate_w[row * GIN + 2048 + i] * rn[e][i];
    rc[e][row] = sum;
  }

  // ---- gate weights -> registers (f16x2): lane l covers pair m = l>>2,
  // rows dd = 16*(l&3) + (4j+k), for 4 gate rows (wave's rows, half-swap) ----
  u32 gw[4][16];
  {
    const int mpair = l >> 2;
    const int dbase = (l & 3) << 4;
#pragma unroll
    for (int rr = 0; rr < 4; ++rr) {
      const int grow = (w << 2) + (rr ^ (H << 1));
      const float* wp = gate_w + grow * GIN + 2 * mpair;
#pragma unroll
      for (int e = 0; e < 16; ++e) {
        int col = (dbase + e) * 32;
        gw[rr][e] = pkf16(wp[col], wp[col + 1]);
      }
    }
  }
  const float gb = gate_b[d];

  // ---- packed sign masks mA[m]: lo sign = sbl(m), hi sign = sbl(m)^flip,
  // flip = popc(m)&1 ? pc : pc^1  (R6/R8-verified parity rule) ----
  const int pc = __popc(c) & 1;
  u32 mA[16];
#pragma unroll
  for (int m = 0; m < 16; ++m) {
    int nb = gp_negbit(m, m ^ c);
    int flip = (__popc(m) & 1) ? pc : (pc ^ 1);
    mA[m] = (nb ? 0x8000u : 0u) | (((u32)(nb ^ flip)) << 31);
  }
  __syncthreads();

  // per-lane copies selected per step by uniform xi
  float rcv0 = rc[0][d] + gb, rcv1 = rc[1][d] + gb;
  float rcv2 = rc[2][d] + gb, rcv3 = rc[3][d] + gb;
  float iv0 = inv_lds[0], iv1 = inv_lds[1];
  float iv2 = inv_lds[2], iv3 = inv_lds[3];

  // register-resident state: u0 = h[d][c], u1 = h[d][c+16]
  float u0 = (c == 0) ? 1.f : 0.f, u1 = 0.f;

  // ---- main loop; x indices prefetched 2 steps ahead (scalar) ----
  const int* xg = x + b * TT;
  int xiA = uni_i(xg[0]);
  int xiB = uni_i(xg[1]);

  for (int t = 0; t < TT; t += 2) {
    int xiC = uni_i(xg[(t + 2 < TT) ? t + 2 : 0]);
    int xiD = uni_i(xg[(t + 3 < TT) ? t + 3 : 0]);
    STEP(0, xiA);
    STEP(1, xiB);
    xiA = xiC;
    xiB = xiD;
  }

  // ================= fused head =================
  hs[d * 32 + c] = u0;
  hs[d * 32 + c + 16] = u1;
  __syncthreads();

  const int hr = tid >> 3;  // output row 0..127
  const int seg = tid & 7;  // column segment (256 floats)
  float acc = 0.f;
  {
    const float4* w4 = (const float4*)(w1 + hr * 2048 + seg * 256);
    const float4* h4 = (const float4*)(hs + seg * 256);
#pragma unroll 8
    for (int k = 0; k < 64; ++k) {
      float4 a = w4[k], hv = h4[k];
      acc = fmaf(a.x, hv.x, acc);
      acc = fmaf(a.y, hv.y, acc);
      acc = fmaf(a.z, hv.z, acc);
      acc = fmaf(a.w, hv.w, acc);
    }
  }
  acc = dpp_add_f<0xB1>(acc);
  acc = dpp_add_f<0x4E>(acc);
  acc = dpp_add_f<0x141>(acc);  // 8-lane group: all hold full row dot
  float z = acc + b1g[hr];

  // LayerNorm stats over 128 rows (each row appears in 8 lanes -> /1024)
  float s1 = z, s2 = z * z;
  s1 = dpp_add_f<0xB1>(s1); s1 = dpp_add_f<0x4E>(s1);
  s1 = dpp_add_f<0x141>(s1); s1 = dpp_add_f<0x140>(s1);
  s1 = swz_add16(s1); s1 += bpermf(bp32, s1);
  s2 = dpp_add_f<0xB1>(s2); s2 = dpp_add_f<0x4E>(s2);
  s2 = dpp_add_f<0x141>(s2); s2 = dpp_add_f<0x140>(s2);
  s2 = swz_add16(s2); s2 += bpermf(bp32, s2);
  if (l == 0) { redA[w][0] = s1; redA[w][1] = s2; }
  __syncthreads();
  float tot1 = 0.f, tot2 = 0.f;
#pragma unroll
  for (int k = 0; k < 16; ++k) { tot1 += redA[k][0]; tot2 += redA[k][1]; }
  float mu = tot1 * (1.f / 1024.f);
  float var = tot2 * (1.f / 1024.f) - mu * mu;
  z = (z - mu) * rsqrtf(var + 1e-5f) * ln_g[hr] + ln_b[hr];
  z = fmaxf(z, 0.f);

  float c0 = (seg == 0) ? z * w2[hr] : 0.f;
  float c1 = (seg == 0) ? z * w2[128 + hr] : 0.f;
  c0 = dpp_add_f<0xB1>(c0); c0 = dpp_add_f<0x4E>(c0);
  c0 = dpp_add_f<0x141>(c0); c0 = dpp_add_f<0x140>(c0);
  c0 = swz_add16(c0); c0 += bpermf(bp32, c0);
  c1 = dpp_add_f<0xB1>(c1); c1 = dpp_add_f<0x4E>(c1);
  c1 = dpp_add_f<0x141>(c1); c1 = dpp_add_f<0x140>(c1);
  c1 = swz_add16(c1); c1 += bpermf(bp32, c1);
  if (l == 0) { redB[w][0] = c0; redB[w][1] = c1; }
  __syncthreads();
  if (tid == 0) {
    float p0 = 0.f, p1 = 0.f;
#pragma unroll
    for (int k = 0; k < 16; ++k) { p0 += redB[k][0]; p1 += redB[k][1]; }
    out[b * 2 + 0] = p0 + b2[0];
    out[b * 2 + 1] = p1 + b2[1];
  }
}

extern "C" void kernel_launch(void* const* d_in, const int* in_sizes, int n_in,
                              void* d_out, int out_size, void* d_ws,
                              size_t ws_size, hipStream_t stream) {
  (void)in_sizes; (void)n_in; (void)out_size; (void)ws_size;
  const int* x = (const int*)d_in[0];
  const float* emb = (const float*)d_in[1];
  const float* gate_w = (const float*)d_in[2];
  const float* gate_b = (const float*)d_in[3];
  const float* w1 = (const float*)d_in[4];
  const float* b1 = (const float*)d_in[5];
  const float* ln_g = (const float*)d_in[6];
  const float* ln_b = (const float*)d_in[7];
  const float* w2 = (const float*)d_in[8];
  const float* b2 = (const float*)d_in[9];
  float* out = (float*)d_out;
  u32* wsu = (u32*)d_ws;  // 64 dwords: packed raw emb rows

  versor_pre<<<dim3(1), dim3(64), 0, stream>>>(emb, wsu);
  versor_fused<<<dim3(BB), dim3(1024), 0, stream>>>(
      x, emb, gate_w, gate_b, w1, b1, ln_g, ln_b, w2, b2, wsu, out);
}

// Round 10
// 840.975 us; speedup vs baseline: 1.4367x; 1.4367x over previous
//
#include <hip/hip_runtime.h>
#include <hip/hip_fp16.h>

typedef unsigned int u32;
typedef _Float16 h2f __attribute__((ext_vector_type(2)));

#define BB 128
#define TT 512
#define DD 64
#define NBL 32
#define GIN 2080

// DPP: quad_perm xor1=0xB1 xor2=0x4E xor3=0x1B; half_mirror(rev8)=0x141;
// row_mirror(rev16)=0x140. All VALU-pipe.
template <int CTRL>
__device__ __forceinline__ float dpp_mov_f(float x) {
  return __builtin_bit_cast(
      float, __builtin_amdgcn_update_dpp(0, __builtin_bit_cast(int, x), CTRL,
                                         0xF, 0xF, true));
}
template <int CTRL>
__device__ __forceinline__ float dpp_add_f(float x) {
  return x + dpp_mov_f<CTRL>(x);
}
__device__ __forceinline__ float swz_add16(float x) {  // xor16 within 32
  return x + __builtin_bit_cast(float, __builtin_amdgcn_ds_swizzle(
                                           __builtin_bit_cast(int, x), 0x401F));
}
__device__ __forceinline__ float bpermf(int addr, float x) {
  return __builtin_bit_cast(
      float, __builtin_amdgcn_ds_bpermute(addr, __builtin_bit_cast(int, x)));
}
__device__ __forceinline__ float xorf(float a, u32 m) {
  return __builtin_bit_cast(float, __builtin_bit_cast(u32, a) ^ m);
}
__device__ __forceinline__ float uni_f(float v) {
  return __builtin_bit_cast(
      float, __builtin_amdgcn_readfirstlane(__builtin_bit_cast(int, v)));
}
__device__ __forceinline__ int uni_i(int v) {
  return __builtin_amdgcn_readfirstlane(v);
}

// sign of e_i * e_j in Cl(4,1): 1 if negative
__device__ inline int gp_negbit(int i, int j) {
  int sw = 0;
#pragma unroll
  for (int b = 0; b < 5; ++b)
    if ((j >> b) & 1) sw += __popc(i >> (b + 1));
  return (sw ^ ((i & j) >> 4)) & 1;  // METRIC[4] = -1
}

__device__ inline float fdot2f(u32 a, u32 b, float acc) {
#if __has_builtin(__builtin_amdgcn_fdot2)
  return __builtin_amdgcn_fdot2(__builtin_bit_cast(h2f, a),
                                __builtin_bit_cast(h2f, b), acc, false);
#else
  h2f av = __builtin_bit_cast(h2f, a), bv = __builtin_bit_cast(h2f, b);
  return acc + (float)av.x * (float)bv.x + (float)av.y * (float)bv.y;
#endif
}

__device__ inline u32 pkf16(float a, float b) {
  return __builtin_bit_cast(u32, __builtin_amdgcn_cvt_pkrtz(a, b));
}

// One recurrence step: R2-verified math (f32 GP, LDS hq + h16t gate), with
// R3-verified raw-emb scalars (RNR in SGPRs) and inv-norm folded post-dot.
#define STEP(P, RNR, XI)                                                      \
  do {                                                                        \
    const int pn = (P) ^ 1;                                                   \
    /* gate: 8x b128 LDS reads + 128 f16 dot2 (R2-verified mapping) */        \
    const u32* Hb = &h16t[(P)][s >> 1][(s & 1) << 5];                         \
    float a0 = 0.f, a1 = 0.f, a2 = 0.f, a3 = 0.f;                             \
    _Pragma("unroll") for (int jq = 0; jq < 8; ++jq) {                        \
      uint4 hv = *(const uint4*)(Hb + (jq << 2));                             \
      a0 = fdot2f(gw[0][4 * jq + 0], hv.x, a0);                               \
      a0 = fdot2f(gw[0][4 * jq + 1], hv.y, a0);                               \
      a0 = fdot2f(gw[0][4 * jq + 2], hv.z, a0);                               \
      a0 = fdot2f(gw[0][4 * jq + 3], hv.w, a0);                               \
      a1 = fdot2f(gw[1][4 * jq + 0], hv.x, a1);                               \
      a1 = fdot2f(gw[1][4 * jq + 1], hv.y, a1);                               \
      a1 = fdot2f(gw[1][4 * jq + 2], hv.z, a1);                               \
      a1 = fdot2f(gw[1][4 * jq + 3], hv.w, a1);                               \
      a2 = fdot2f(gw[2][4 * jq + 0], hv.x, a2);                               \
      a2 = fdot2f(gw[2][4 * jq + 1], hv.y, a2);                               \
      a2 = fdot2f(gw[2][4 * jq + 2], hv.z, a2);                               \
      a2 = fdot2f(gw[2][4 * jq + 3], hv.w, a2);                               \
      a3 = fdot2f(gw[3][4 * jq + 0], hv.x, a3);                               \
      a3 = fdot2f(gw[3][4 * jq + 1], hv.y, a3);                               \
      a3 = fdot2f(gw[3][4 * jq + 2], hv.z, a3);                               \
      a3 = fdot2f(gw[3][4 * jq + 3], hv.w, a3);                               \
    }                                                                         \
    a0 = dpp_add_f<0xB1>(a0); a0 = dpp_add_f<0x4E>(a0);                       \
    a0 = dpp_add_f<0x141>(a0); a0 = dpp_add_f<0x140>(a0); a0 = swz_add16(a0); \
    a1 = dpp_add_f<0xB1>(a1); a1 = dpp_add_f<0x4E>(a1);                       \
    a1 = dpp_add_f<0x141>(a1); a1 = dpp_add_f<0x140>(a1); a1 = swz_add16(a1); \
    a2 = dpp_add_f<0xB1>(a2); a2 = dpp_add_f<0x4E>(a2);                       \
    a2 = dpp_add_f<0x141>(a2); a2 = dpp_add_f<0x140>(a2); a2 = swz_add16(a2); \
    a3 = dpp_add_f<0xB1>(a3); a3 = dpp_add_f<0x4E>(a3);                       \
    a3 = dpp_add_f<0x141>(a3); a3 = dpp_add_f<0x140>(a3); a3 = swz_add16(a3); \
    const int jsel = rl & 3;                                                  \
    float zv = (jsel == 0) ? a0 : (jsel == 1) ? a1 : (jsel == 2) ? a2 : a3;   \
    float rcsel = ((XI) == 0)   ? rcv0                                        \
                  : ((XI) == 1) ? rcv1                                        \
                  : ((XI) == 2) ? rcv2                                        \
                                : rcv3;                                       \
    float invsel = ((XI) == 0)   ? iv0                                        \
                   : ((XI) == 1) ? iv1                                        \
                   : ((XI) == 2) ? iv2                                        \
                                 : iv3;                                       \
    float g = 1.f / (1.f + exp2f(-1.44269504f * (zv + rcsel)));               \
    /* GP: hq[q] = h[d] owner quads from LDS (DS pipe), R2-verified signs */  \
    float4 hq[8];                                                             \
    _Pragma("unroll") for (int q = 0; q < 8; ++q)                             \
        hq[q] = *(const float4*)&h32[(P)][d][(q ^ c) << 2];                   \
    float b0 = 0.f, b1v = 0.f, b2v = 0.f, b3v = 0.f;                          \
    _Pragma("unroll") for (int q = 0; q < 8; ++q) {                           \
      float t0 = xorf(RNR[q], sb[q]);                                         \
      float t1 = xorf(RNR[q + 8], sb[q + 8]);                                 \
      float t2 = xorf(RNR[q + 16], sb[q + 16]);                               \
      float t3 = xorf(RNR[q + 24], sb[q + 24]);                               \
      b0 = fmaf(t0, hq[q].x, b0);                                             \
      b1v = fmaf(t0, hq[q].y, b1v);                                           \
      b2v = fmaf(t0, hq[q].z, b2v);                                           \
      b3v = fmaf(t0, hq[q].w, b3v);                                           \
      b0 = fmaf(t1, hq[q].y, b0);                                             \
      b1v = fmaf(t1, hq[q].x, b1v);                                           \
      b2v = fmaf(t1, hq[q].w, b2v);                                           \
      b3v = fmaf(t1, hq[q].z, b3v);                                           \
      b0 = fmaf(t2, hq[q].z, b0);                                             \
      b1v = fmaf(-t2, hq[q].w, b1v);                                          \
      b2v = fmaf(-t2, hq[q].x, b2v);                                          \
      b3v = fmaf(t2, hq[q].y, b3v);                                           \
      b0 = fmaf(t3, hq[q].w, b0);                                             \
      b1v = fmaf(-t3, hq[q].z, b1v);                                          \
      b2v = fmaf(-t3, hq[q].y, b2v);                                          \
      b3v = fmaf(t3, hq[q].x, b3v);                                           \
    }                                                                         \
    /* gated update (R3-verified inv-fold form) + mnorm over 8-lane group */  \
    float gi = g * invsel;                                                    \
    float om = 1.f - g;                                                       \
    float u0 = fmaf(gi, b0, om * hq[0].x);                                    \
    float u1 = fmaf(gi, b1v, om * hq[0].y);                                   \
    float u2 = fmaf(gi, b2v, om * hq[0].z);                                   \
    float u3 = fmaf(gi, b3v, om * hq[0].w);                                   \
    float sq = u0 * u0 + u1 * u1 + u2 * u2 + u3 * u3;                         \
    sq = dpp_add_f<0xB1>(sq);                                                 \
    sq = dpp_add_f<0x4E>(sq);                                                 \
    sq = dpp_add_f<0x141>(sq);                                                \
    float sc = 1.f / (sqrtf(sq) + 1e-8f);                                     \
    u0 *= sc; u1 *= sc; u2 *= sc; u3 *= sc;                                   \
    uf0 = u0; uf1 = u1; uf2 = u2; uf3 = u3;                                   \
    *(float4*)&h32[pn][d][c << 2] = make_float4(u0, u1, u2, u3);              \
    float v0 = dpp_mov_f<0xB1>(u0);                                           \
    float v1 = dpp_mov_f<0xB1>(u1);                                           \
    float v2 = dpp_mov_f<0xB1>(u2);                                           \
    float v3 = dpp_mov_f<0xB1>(u3);                                           \
    if (!(l & 1)) { /* even c packs (c,c+1) */                                \
      h16t[pn][(c) >> 1][d] = pkf16(u0, v0);                                  \
      h16t[pn][(c + 8) >> 1][d] = pkf16(u1, v1);                              \
      h16t[pn][(c + 16) >> 1][d] = pkf16(u2, v2);                             \
      h16t[pn][(c + 24) >> 1][d] = pkf16(u3, v3);                             \
    }                                                                         \
    __syncthreads();                                                          \
  } while (0)

__global__ __launch_bounds__(512, 2) void versor_fused(
    const int* __restrict__ x, const float* __restrict__ emb,
    const float* __restrict__ gate_w, const float* __restrict__ gate_b,
    const float* __restrict__ w1, const float* __restrict__ b1g,
    const float* __restrict__ ln_g, const float* __restrict__ ln_b,
    const float* __restrict__ w2, const float* __restrict__ b2,
    float* __restrict__ out) {
  __shared__ float rn[4][NBL];   // normalized emb rows (init/rc only)
  __shared__ float inv_lds[4];   // 1/(||emb_row||+eps)
  __shared__ float rc[4][DD];    // r-part of gate, pre-dotted
  __shared__ __align__(16) float h32[2][DD][36];  // fp32 h, owner-quad-major
  __shared__ __align__(16) u32 h16t[2][16][68];   // f16x2 h transposed
  __shared__ __align__(16) float hs[2048];        // final h for head
  __shared__ float redA[8][2];
  __shared__ float redB[8][2];

  const int b = blockIdx.x;
  const int tid = threadIdx.x;
  const int w = tid >> 6;       // wave 0..7
  const int l = tid & 63;       // lane
  const int rl = l >> 3;        // 0..7
  const int d = (w << 3) + rl;  // this lane's state row
  const int c = l & 7;          // owner quad: owns blades {c,c+8,c+16,c+24}
  const int r2g = l >> 5;       // gate row-quad group within wave (0..1)
  const int s = l & 31;         // gate 32-dword column slice
  const int bp32 = ((l ^ 32) << 2);

  // ---- init: normalized embeddings + inverse norms ----
  if (tid < 4) {
    float v[NBL];
    float sum = 0.f;
    for (int i = 0; i < NBL; ++i) {
      v[i] = emb[tid * NBL + i];
      sum += v[i] * v[i];
    }
    float sc = 1.f / (sqrtf(sum) + 1e-8f);
    inv_lds[tid] = sc;
    for (int i = 0; i < NBL; ++i) rn[tid][i] = v[i] * sc;
  }
  for (int idx = tid; idx < DD * 36; idx += 512) {
    int dd = idx / 36, jj = idx - dd * 36;
    h32[0][dd][jj] = (jj == 0) ? 1.f : 0.f;  // e0: owner 0, slot 0
  }
  for (int idx = tid; idx < 16 * 68; idx += 512) {
    int m = idx / 68, dd = idx - m * 68;
    h16t[0][m][dd] = (m == 0 && dd < 64) ? 0x00003C00u : 0u;  // pack(1.0h,0)
  }
  __syncthreads();

  // ---- rc[e][row] = sum_i gate_w[row][2048+i] * rn_normalized[e][i] ----
  if (tid < 256) {
    int e = tid >> 6, row = tid & 63;
    float sum = 0.f;
    for (int i = 0; i < NBL; ++i) sum += gate_w[row * GIN + 2048 + i] * rn[e][i];
    rc[e][row] = sum;
  }

  // ---- gate weights -> registers (f16x2), 4 rows x 32 dwords per lane ----
  u32 gw[4][32];
#pragma unroll
  for (int rr = 0; rr < 4; ++rr) {
    const int row = (w << 3) + (r2g << 2) + rr;
    const float* wp = gate_w + row * GIN;
#pragma unroll
    for (int m = 0; m < 32; ++m) {
      int Dd = 32 * s + m;  // h16 dword index = pair*64 + d
      int pair = Dd >> 6, dd = Dd & 63;
      int col = dd * 32 + 2 * pair;
      gw[rr][m] = pkf16(wp[col], wp[col + 1]);
    }
  }
  const float gb = gate_b[d];

  // ---- per-lane sign masks for k=c (i-indexed) ----
  u32 sb[NBL];
#pragma unroll
  for (int i = 0; i < NBL; ++i) sb[i] = gp_negbit(i, i ^ c) ? 0x80000000u : 0u;
  __syncthreads();

  // per-lane copies selected per step by uniform xi (R3/R5-verified)
  const float rcv0 = rc[0][d] + gb, rcv1 = rc[1][d] + gb;
  const float rcv2 = rc[2][d] + gb, rcv3 = rc[3][d] + gb;
  const float iv0 = inv_lds[0], iv1 = inv_lds[1];
  const float iv2 = inv_lds[2], iv3 = inv_lds[3];

  float uf0 = 0.f, uf1 = 0.f, uf2 = 0.f, uf3 = 0.f;  // final state carry

  // ---- software-pipelined scalar loads of x / raw emb rows (R3) ----
  const int* xg = x + b * TT;
  int xiA = uni_i(xg[0]);
  int xiB = uni_i(xg[1]);
  float rnA[NBL], rnB[NBL];
#pragma unroll
  for (int i = 0; i < NBL; ++i) rnA[i] = uni_f(emb[xiA * NBL + i]);

  for (int t = 0; t < TT; t += 2) {
#pragma unroll
    for (int i = 0; i < NBL; ++i) rnB[i] = uni_f(emb[xiB * NBL + i]);
    int xiC = uni_i(xg[(t + 2 < TT) ? t + 2 : 0]);
    STEP(0, rnA, xiA);
#pragma unroll
    for (int i = 0; i < NBL; ++i) rnA[i] = uni_f(emb[xiC * NBL + i]);
    int xiD = uni_i(xg[(t + 3 < TT) ? t + 3 : 0]);
    STEP(1, rnB, xiB);
    xiA = xiC;
    xiB = xiD;
  }

  // ================= fused head (R5-verified, 512 thr) =================
  {
    float* ho = hs + d * 32 + c;
    ho[0] = uf0;
    ho[8] = uf1;
    ho[16] = uf2;
    ho[24] = uf3;
  }
  __syncthreads();

  const int hr = tid >> 2;  // output row 0..127
  const int seg = tid & 3;  // column segment (512 floats)
  float acc = 0.f;
  {
    const float4* w4 = (const float4*)(w1 + hr * 2048 + seg * 512);
    const float4* h4 = (const float4*)(hs + seg * 512);
#pragma unroll 8
    for (int k = 0; k < 128; ++k) {
      float4 a = w4[k], hv = h4[k];
      acc = fmaf(a.x, hv.x, acc);
      acc = fmaf(a.y, hv.y, acc);
      acc = fmaf(a.z, hv.z, acc);
      acc = fmaf(a.w, hv.w, acc);
    }
  }
  acc = dpp_add_f<0xB1>(acc);
  acc = dpp_add_f<0x4E>(acc);  // all 4 lanes of the quad hold full row dot
  float z = acc + b1g[hr];

  // LayerNorm stats over 128 rows (each row appears in 4 lanes -> /512)
  float s1 = z, s2 = z * z;
  s1 = dpp_add_f<0xB1>(s1); s1 = dpp_add_f<0x4E>(s1);
  s1 = dpp_add_f<0x141>(s1); s1 = dpp_add_f<0x140>(s1);
  s1 = swz_add16(s1); s1 += bpermf(bp32, s1);
  s2 = dpp_add_f<0xB1>(s2); s2 = dpp_add_f<0x4E>(s2);
  s2 = dpp_add_f<0x141>(s2); s2 = dpp_add_f<0x140>(s2);
  s2 = swz_add16(s2); s2 += bpermf(bp32, s2);
  if (l == 0) { redA[w][0] = s1; redA[w][1] = s2; }
  __syncthreads();
  float tot1 = 0.f, tot2 = 0.f;
#pragma unroll
  for (int k = 0; k < 8; ++k) { tot1 += redA[k][0]; tot2 += redA[k][1]; }
  float mu = tot1 * (1.f / 512.f);
  float var = tot2 * (1.f / 512.f) - mu * mu;
  z = (z - mu) * rsqrtf(var + 1e-5f) * ln_g[hr] + ln_b[hr];
  z = fmaxf(z, 0.f);

  float c0 = (seg == 0) ? z * w2[hr] : 0.f;
  float c1 = (seg == 0) ? z * w2[128 + hr] : 0.f;
  c0 = dpp_add_f<0xB1>(c0); c0 = dpp_add_f<0x4E>(c0);
  c0 = dpp_add_f<0x141>(c0); c0 = dpp_add_f<0x140>(c0);
  c0 = swz_add16(c0); c0 += bpermf(bp32, c0);
  c1 = dpp_add_f<0xB1>(c1); c1 = dpp_add_f<0x4E>(c1);
  c1 = dpp_add_f<0x141>(c1); c1 = dpp_add_f<0x140>(c1);
  c1 = swz_add16(c1); c1 += bpermf(bp32, c1);
  if (l == 0) { redB[w][0] = c0; redB[w][1] = c1; }
  __syncthreads();
  if (tid == 0) {
    float p0 = 0.f, p1 = 0.f;
#pragma unroll
    for (int k = 0; k < 8; ++k) { p0 += redB[k][0]; p1 += redB[k][1]; }
    out[b * 2 + 0] = p0 + b2[0];
    out[b * 2 + 1] = p1 + b2[1];
  }
}

extern "C" void kernel_launch(void* const* d_in, const int* in_sizes, int n_in,
                              void* d_out, int out_size, void* d_ws,
                              size_t ws_size, hipStream_t stream) {
  (void)in_sizes; (void)n_in; (void)out_size; (void)d_ws; (void)ws_size;
  const int* x = (const int*)d_in[0];
  const float* emb = (const float*)d_in[1];
  const float* gate_w = (const float*)d_in[2];
  const float* gate_b = (const float*)d_in[3];
  const float* w1 = (const float*)d_in[4];
  const float* b1 = (const float*)d_in[5];
  const float* ln_g = (const float*)d_in[6];
  const float* ln_b = (const float*)d_in[7];
  const float* w2 = (const float*)d_in[8];
  const float* b2 = (const float*)d_in[9];
  float* out = (float*)d_out;

  versor_fused<<<dim3(BB), dim3(512), 0, stream>>>(
      x, emb, gate_w, gate_b, w1, b1, ln_g, ln_b, w2, b2, out);
}